// Round 2
// baseline (352.470 us; speedup 1.0000x reference)
//
#include <hip/hip_runtime.h>
#include <hip/hip_bf16.h>
#include <math.h>

// CausalSelfAttention  B=4, S=2048, D=1024, H=16, HD=64
// R8: attn_chunk: K/V LDS staging REMOVED entirely.
//     - K and V B-fragments loaded straight from global (16B/lane, L1/L2-served;
//       identical frags across the 4 waves -> L1 dedup). Guide common-mistake #7.
//     - Zero __syncthreads in the main loop (Ps is wave-private).
//     - LDS = Ps only (18.4 KB) -> occupancy VGPR-limited (~3 waves/SIMD) instead
//       of LDS-limited (was 51.7 KB -> 3 blocks/CU with barriers).
//     - mask bias loaded per-lane from global (amask L1-hot), mb[] LDS removed.
//     QBLK=128 (4 waves x 32 q rows) and split-K scheme kept from R7.
//     qkv/convert/combine unchanged.

#define B_ 4
#define S_ 2048
#define D_ 1024
#define H_ 16
#define HD_ 64
#define M_ (B_ * S_)   // 8192

typedef unsigned short u16;
typedef unsigned int u32;
typedef __attribute__((ext_vector_type(4))) float f32x4;
typedef __attribute__((ext_vector_type(8))) short bf16x8;   // 8 bf16 in 4 VGPRs

__device__ __forceinline__ u16 f2bfu_rn(float x) {
    u32 u = __builtin_bit_cast(u32, x);
    return (u16)((u + 0x8000u) >> 16);
}

__device__ __forceinline__ void gl2lds16(const void* g, void* l) {
    __builtin_amdgcn_global_load_lds(
        (const __attribute__((address_space(1))) u32*)g,
        (__attribute__((address_space(3))) u32*)l, 16, 0, 0);
}

// ---------------------------------------------------------------------------
// fp32 -> bf16 conversion, 8 elems/thread
// ---------------------------------------------------------------------------
#define XN  8388608u    // 8192*1024
#define WN  1048576u    // 1024*1024
__global__ __launch_bounds__(256) void convert_bf16(
    const float* __restrict__ X,  const float* __restrict__ Wq,
    const float* __restrict__ Wk, const float* __restrict__ Wv,
    u16* __restrict__ Xb, u16* __restrict__ Wqb,
    u16* __restrict__ Wkb, u16* __restrict__ Wvb)
{
    size_t idx = ((size_t)blockIdx.x * 256 + threadIdx.x) * 8;
    const float* src; u16* dst; size_t off;
    if (idx < XN)                { src = X;  dst = Xb;  off = idx; }
    else if (idx < XN + WN)      { src = Wq; dst = Wqb; off = idx - XN; }
    else if (idx < XN + 2 * WN)  { src = Wk; dst = Wkb; off = idx - XN - WN; }
    else                         { src = Wv; dst = Wvb; off = idx - XN - 2 * WN; }
    float4 a = *(const float4*)(src + off);
    float4 b = *(const float4*)(src + off + 4);
    uint4 o;
    o.x = (u32)f2bfu_rn(a.x) | ((u32)f2bfu_rn(a.y) << 16);
    o.y = (u32)f2bfu_rn(a.z) | ((u32)f2bfu_rn(a.w) << 16);
    o.z = (u32)f2bfu_rn(b.x) | ((u32)f2bfu_rn(b.y) << 16);
    o.w = (u32)f2bfu_rn(b.z) | ((u32)f2bfu_rn(b.w) << 16);
    *(uint4*)(dst + off) = o;
}

// ---------------------------------------------------------------------------
// QKV projection GEMM: 128x128 tile, BK=64, 4 waves (2x2), 16x16x32 MFMA,
// both operands staged via global_load_lds w/ XOR swizzle.
// z=0: Q = (X Wq^T + bq)*0.125*log2e -> [bh][s][hd]
// z=1: K =  X Wk^T + bk              -> [bh][s][hd]
// z=2: V^T = Wv X^T (+ bv)           -> [bh][hd][s]
// ---------------------------------------------------------------------------
#define QSCALE 0.18033688011112042f   // 0.125 * log2(e)

__global__ __launch_bounds__(256) void qkv_mfma(
    const u16* __restrict__ Xb,
    const u16* __restrict__ Wqb, const u16* __restrict__ Wkb,
    const u16* __restrict__ Wvb,
    const float* __restrict__ bq, const float* __restrict__ bk,
    const float* __restrict__ bv,
    u16* __restrict__ Qb, u16* __restrict__ Kb, u16* __restrict__ Vtb)
{
    const int which = blockIdx.z;
    const u16* Asrc; const u16* Bsrc; const float* bias; u16* Out;
    int m0, n0;
    if (which == 0)      { Asrc = Xb;  Bsrc = Wqb; bias = bq; Out = Qb;
                           m0 = blockIdx.y * 128; n0 = blockIdx.x * 128; }
    else if (which == 1) { Asrc = Xb;  Bsrc = Wkb; bias = bk; Out = Kb;
                           m0 = blockIdx.y * 128; n0 = blockIdx.x * 128; }
    else                 { Asrc = Wvb; Bsrc = Xb;  bias = bv; Out = Vtb;
                           m0 = blockIdx.x * 128; n0 = blockIdx.y * 128; }

    __shared__ u16 As[128][64];
    __shared__ u16 Bs[128][64];

    const int t = threadIdx.x;
    const int wave = t >> 6, lane = t & 63;
    const int qd = lane >> 4, l15 = lane & 15;
    const int wm = wave >> 1, wn = wave & 1;

    const f32x4 zero = {0.f, 0.f, 0.f, 0.f};
    f32x4 acc[4][4];
#pragma unroll
    for (int i = 0; i < 4; ++i)
#pragma unroll
        for (int j = 0; j < 4; ++j) acc[i][j] = zero;

    for (int k0 = 0; k0 < D_; k0 += 64) {
        __syncthreads();
#pragma unroll
        for (int i = 0; i < 4; ++i) {
            int r0  = (wave * 4 + i) * 8;
            int row = r0 + (lane >> 3);
            int g   = (lane & 7) ^ (row & 7);
            gl2lds16(Asrc + (size_t)(m0 + row) * D_ + k0 + g * 8, &As[r0][0]);
            gl2lds16(Bsrc + (size_t)(n0 + row) * D_ + k0 + g * 8, &Bs[r0][0]);
        }
        __syncthreads();
#pragma unroll
        for (int ks = 0; ks < 2; ++ks) {
            bf16x8 af[4], bf[4];
#pragma unroll
            for (int mt = 0; mt < 4; ++mt) {
                int row = wm * 64 + mt * 16 + l15;
                int p = (ks * 4 + qd) ^ (row & 7);
                af[mt] = *(const bf16x8*)&As[row][p * 8];
            }
#pragma unroll
            for (int nt = 0; nt < 4; ++nt) {
                int row = wn * 64 + nt * 16 + l15;
                int p = (ks * 4 + qd) ^ (row & 7);
                bf[nt] = *(const bf16x8*)&Bs[row][p * 8];
            }
#pragma unroll
            for (int mt = 0; mt < 4; ++mt)
#pragma unroll
                for (int nt = 0; nt < 4; ++nt)
                    acc[mt][nt] = __builtin_amdgcn_mfma_f32_16x16x32_bf16(
                        af[mt], bf[nt], acc[mt][nt], 0, 0, 0);
        }
    }

    // epilogue: C/D layout row = qd*4 + reg, col = l15
    if (which < 2) {
#pragma unroll
        for (int nt = 0; nt < 4; ++nt) {
            int n = n0 + wn * 64 + nt * 16 + l15;      // feature
            float bv_ = bias[n];
            int h = n >> 6, hd = n & 63;
#pragma unroll
            for (int mt = 0; mt < 4; ++mt)
#pragma unroll
                for (int r = 0; r < 4; ++r) {
                    int m = m0 + wm * 64 + mt * 16 + qd * 4 + r;  // token
                    int bb = m >> 11, s = m & 2047;
                    float v = acc[mt][nt][r] + bv_;
                    if (which == 0) v *= QSCALE;
                    Out[(((size_t)(bb * H_ + h)) * S_ + s) * HD_ + hd] = f2bfu_rn(v);
                }
        }
    } else {
#pragma unroll
        for (int mt = 0; mt < 4; ++mt)
#pragma unroll
            for (int r = 0; r < 4; ++r) {
                int f = m0 + wm * 64 + mt * 16 + qd * 4 + r;      // feature
                float bv_ = bias[f];
                int h = f >> 6, hd = f & 63;
#pragma unroll
                for (int nt = 0; nt < 4; ++nt) {
                    int tok = n0 + wn * 64 + nt * 16 + l15;       // token
                    int bb = tok >> 11, s = tok & 2047;
                    float v = acc[mt][nt][r] + bv_;
                    Out[(((size_t)(bb * H_ + h)) * HD_ + hd) * S_ + s] = f2bfu_rn(v);
                }
            }
    }
}

// ---------------------------------------------------------------------------
// Split-K flash attention, deterministic (plain stores only), BARRIER-FREE.
// QBLK=128 q rows per block (16 q-blocks qi=0..15), key tiles of 64.
// jtmax(qi) = 2*qi+1.
//   chunk0: tiles 0..min(jtmax,15).  qi<=7 -> full row, store normalized.
//           qi>=8 -> unnormalized O -> out, l -> L0.
//   chunk1 (qi>=8): tiles 16..jtmax -> Opart/L1.  (rows >= 1024 only)
// blockIdx.x in [0,24) maps heavy-first (see R7 comment).
// K and V fragments are read directly from global memory (no LDS staging):
//   K frag: Kg[(j0+nt*16+l15)*HD + ks*32+qd*8]   (16B per lane)
//   V frag: Vg[(nt*16+l15)*S + j0+ks*32+qd*8]    (16B per lane)
// All 4 waves read identical frags -> L1 dedup; tiles are L2-resident.
// Only LDS use: Ps (wave-private P round-trip for the PV A-operand).
// ---------------------------------------------------------------------------
__global__ __launch_bounds__(256) void attn_chunk(
    const u16* __restrict__ Qb, const u16* __restrict__ Kb,
    const u16* __restrict__ Vtb, const int* __restrict__ amask,
    float* __restrict__ Oout, float* __restrict__ Opart,
    float* __restrict__ L0, float* __restrict__ L1)
{
    const int x = blockIdx.x;
    const int bh = blockIdx.y;
    const int b = bh >> 4, h = bh & 15;

    int qi; bool second;
    if (x < 9)       { qi = 15 - x; second = false; }
    else if (x == 9) { qi = 15;     second = true;  }
    else {
        int p = x - 10, pi = p >> 1;
        second = (p & 1) != 0;
        qi = second ? (14 - pi) : (6 - pi);
    }
    const int q0    = qi * 128;
    const int jtmax = 2 * qi + 1;
    const int jt0   = second ? 16 : 0;
    const int jt1   = second ? jtmax : min(jtmax, 15);

    const int t = threadIdx.x;
    const int wave = t >> 6, lane = t & 63;
    const int qd = lane >> 4, l15 = lane & 15;

    __shared__ u16 Ps[128][72];      // [q][key] padded (+8); wave-private rows

    const size_t base = (size_t)bh * S_ * HD_;
    const u16* Qg = Qb + base;
    const u16* Kg = Kb + base;
    const u16* Vg = Vtb + base;      // rows = hd, cols = s
    const int* am = amask + b * S_;

    // Q A-frags straight from global: 2 row-tiles of 16 per wave (32 q rows)
    bf16x8 qf[2][2];
#pragma unroll
    for (int mt = 0; mt < 2; ++mt) {
        const u16* qrow = Qg + (size_t)(q0 + wave * 32 + mt * 16 + l15) * HD_;
        qf[mt][0] = *(const bf16x8*)(qrow + qd * 8);
        qf[mt][1] = *(const bf16x8*)(qrow + 32 + qd * 8);
    }
    bf16x8 onesf;
    {
        short v = (l15 == 0) ? (short)0x3F80 : (short)0;
        onesf = (bf16x8){v, v, v, v, v, v, v, v};
    }

    // per-lane fragment base pointers (element units)
    const u16* kp = Kg + (size_t)l15 * HD_ + qd * 8;  // + (j0+nt*16)*HD + ks*32
    const u16* vp = Vg + (size_t)l15 * S_  + qd * 8;  // + nt*16*S + j0 + ks*32

    const f32x4 zero = {0.f, 0.f, 0.f, 0.f};
    f32x4 o[2][5];                   // [row-tile][4 hd tiles + l tile]
#pragma unroll
    for (int mt = 0; mt < 2; ++mt)
#pragma unroll
        for (int i = 0; i < 5; ++i) o[mt][i] = zero;

    for (int jt = jt0; jt <= jt1; ++jt) {
        const int j0 = jt * 64;

        // ---- K fragments from global ----
        bf16x8 kf[2][4];
#pragma unroll
        for (int ks = 0; ks < 2; ++ks)
#pragma unroll
            for (int nt = 0; nt < 4; ++nt)
                kf[ks][nt] = *(const bf16x8*)(kp + (size_t)(j0 + nt * 16) * HD_ + ks * 32);

        // ---- mask bias (amask is L1-hot; 4 coalesced dword loads) ----
        float bias[4];
#pragma unroll
        for (int nt = 0; nt < 4; ++nt)
            bias[nt] = (am[j0 + nt * 16 + l15] == 0) ? -1e30f : 0.0f;

        // ---- S = Q K^T ----
        f32x4 sacc[2][4];
#pragma unroll
        for (int mt = 0; mt < 2; ++mt)
#pragma unroll
            for (int nt = 0; nt < 4; ++nt) sacc[mt][nt] = zero;
        __builtin_amdgcn_s_setprio(1);
#pragma unroll
        for (int ks = 0; ks < 2; ++ks)
#pragma unroll
            for (int nt = 0; nt < 4; ++nt)
#pragma unroll
                for (int mt = 0; mt < 2; ++mt)
                    sacc[mt][nt] = __builtin_amdgcn_mfma_f32_16x16x32_bf16(
                        qf[mt][ks], kf[ks][nt], sacc[mt][nt], 0, 0, 0);
        __builtin_amdgcn_s_setprio(0);

        // ---- V fragments from global (issued early; latency hides under
        //      the softmax VALU work below) ----
        bf16x8 vf[2][4];
#pragma unroll
        for (int ks = 0; ks < 2; ++ks)
#pragma unroll
            for (int nt = 0; nt < 4; ++nt)
                vf[ks][nt] = *(const bf16x8*)(vp + (size_t)(nt * 16) * S_ + j0 + ks * 32);

        // ---- bias + causal + exp2 -> Ps (wave-private rows, no barrier) ----
        const bool nearDiag = (jt >= 2 * qi);
        const int dq = q0 - j0;               // diag tiles: col > prow + dq masked
#pragma unroll
        for (int mt = 0; mt < 2; ++mt)
#pragma unroll
            for (int r = 0; r < 4; ++r) {
                int prow = wave * 32 + mt * 16 + qd * 4 + r;
#pragma unroll
                for (int nt = 0; nt < 4; ++nt) {
                    int col = nt * 16 + l15;
                    float s = sacc[mt][nt][r] + bias[nt];
                    if (nearDiag && col > prow + dq) s = -1e30f;
                    float p = __builtin_amdgcn_exp2f(s);
                    Ps[prow][col] = f2bfu_rn(p);
                }
            }

        // ---- O += P V ; l += P ones (same-wave LDS rows, no barrier) ----
        __builtin_amdgcn_s_setprio(1);
#pragma unroll
        for (int ks = 0; ks < 2; ++ks) {
            bf16x8 pf[2];
#pragma unroll
            for (int mt = 0; mt < 2; ++mt)
                pf[mt] = *(const bf16x8*)&Ps[wave * 32 + mt * 16 + l15][ks * 32 + qd * 8];
#pragma unroll
            for (int nt = 0; nt < 4; ++nt)
#pragma unroll
                for (int mt = 0; mt < 2; ++mt)
                    o[mt][nt] = __builtin_amdgcn_mfma_f32_16x16x32_bf16(
                        pf[mt], vf[ks][nt], o[mt][nt], 0, 0, 0);
#pragma unroll
            for (int mt = 0; mt < 2; ++mt)
                o[mt][4] = __builtin_amdgcn_mfma_f32_16x16x32_bf16(
                    pf[mt], onesf, o[mt][4], 0, 0, 0);
        }
        __builtin_amdgcn_s_setprio(0);
    }

    // ---- epilogue: plain stores (each destination written by ONE block) ----
    if (!second) {
        if (qi <= 7) {
            // full key range: store normalized final value
#pragma unroll
            for (int mt = 0; mt < 2; ++mt)
#pragma unroll
                for (int r = 0; r < 4; ++r) {
                    float l = __shfl(o[mt][4][r], lane & 48);
                    float inv = 1.0f / l;
                    int q = q0 + wave * 32 + mt * 16 + qd * 4 + r;
                    float* op = Oout + ((size_t)(b * S_ + q)) * D_ + h * HD_;
#pragma unroll
                    for (int nt = 0; nt < 4; ++nt)
                        op[nt * 16 + l15] = o[mt][nt][r] * inv;
                }
        } else {
            // partial: unnormalized O -> Oout, l -> L0
#pragma unroll
            for (int mt = 0; mt < 2; ++mt)
#pragma unroll
                for (int r = 0; r < 4; ++r) {
                    int q = q0 + wave * 32 + mt * 16 + qd * 4 + r;
                    float* op = Oout + ((size_t)(b * S_ + q)) * D_ + h * HD_;
#pragma unroll
                    for (int nt = 0; nt < 4; ++nt)
                        op[nt * 16 + l15] = o[mt][nt][r];
                    if (l15 == 0) L0[(size_t)bh * S_ + q] = o[mt][4][r];
                }
        }
    } else {
#pragma unroll
        for (int mt = 0; mt < 2; ++mt)
#pragma unroll
            for (int r = 0; r < 4; ++r) {
                int q = q0 + wave * 32 + mt * 16 + qd * 4 + r;
                int sh = q - 1024;
                float* op = Opart + ((size_t)bh * 1024 + sh) * HD_;
#pragma unroll
                for (int nt = 0; nt < 4; ++nt)
                    op[nt * 16 + l15] = o[mt][nt][r];
                if (l15 == 0) L1[(size_t)bh * 1024 + sh] = o[mt][4][r];
            }
    }
}

// ---------------------------------------------------------------------------
// combine: rows s >= 1024 only.  out = (out + Opart) / (L0 + L1).
// i indexes [b][s-1024][d] flat, float4 per thread.
// ---------------------------------------------------------------------------
__global__ __launch_bounds__(256) void combine(
    float* __restrict__ out, const float* __restrict__ Opart,
    const float* __restrict__ L0, const float* __restrict__ L1)
{
    size_t i = ((size_t)blockIdx.x * 256 + threadIdx.x) * 4;
    int d  = (int)(i & (D_ - 1));
    int bs = (int)(i >> 10);          // b*1024 + (s-1024)
    int b  = bs >> 10, sh = bs & 1023;
    int s  = sh + 1024;
    int h  = d >> 6;
    int bh = b * H_ + h;
    float l = L0[(size_t)bh * S_ + s] + L1[(size_t)bh * 1024 + sh];
    float inv = 1.0f / l;
    float* op = out + ((size_t)(b * S_ + s)) * D_ + d;
    const float* pp = Opart + ((size_t)bh * 1024 + sh) * HD_ + (d & 63);
    float4 v = *(float4*)op;
    float4 p = *(const float4*)pp;
    v.x = (v.x + p.x) * inv; v.y = (v.y + p.y) * inv;
    v.z = (v.z + p.z) * inv; v.w = (v.w + p.w) * inv;
    *(float4*)op = v;
}

// ---------------------------------------------------------------------------
extern "C" void kernel_launch(void* const* d_in, const int* in_sizes, int n_in,
                              void* d_out, int out_size, void* d_ws, size_t ws_size,
                              hipStream_t stream) {
    (void)in_sizes; (void)n_in; (void)out_size; (void)ws_size;
    const float* X    = (const float*)d_in[0];
    const int*   mask = (const int*)d_in[1];
    const float* Wq   = (const float*)d_in[2];
    const float* bq   = (const float*)d_in[3];
    const float* Wk   = (const float*)d_in[4];
    const float* bk   = (const float*)d_in[5];
    const float* Wv   = (const float*)d_in[6];
    const float* bv   = (const float*)d_in[7];
    float* out = (float*)d_out;

    u16* Xb  = (u16*)d_ws;                 // 8192x1024 bf16
    u16* Wqb = Xb  + XN;                   // 1024x1024 bf16
    u16* Wkb = Wqb + WN;
    u16* Wvb = Wkb + WN;
    u16* Qb  = Wvb + WN;                   // [bh][s][hd]  (pre-scaled by QSCALE)
    u16* Kb  = Qb  + XN;
    u16* Vtb = Kb  + XN;                   // [bh][hd][s]
    float* Opart = (float*)(Vtb + XN);     // [bh][1024][64] fp32 (16.8 MB)
    float* L0 = Opart + (size_t)64 * 1024 * 64;   // [bh][2048]
    float* L1 = L0 + (size_t)64 * 2048;           // [bh][1024]

    convert_bf16<<<(XN + 3 * WN) / (256 * 8), 256, 0, stream>>>(
        X, Wq, Wk, Wv, Xb, Wqb, Wkb, Wvb);
    qkv_mfma<<<dim3(D_ / 128, M_ / 128, 3), 256, 0, stream>>>(
        Xb, Wqb, Wkb, Wvb, bq, bk, bv, Qb, Kb, Vtb);
    attn_chunk<<<dim3(24, B_ * H_), 256, 0, stream>>>(
        Qb, Kb, Vtb, mask, out, Opart, L0, L1);
    combine<<<(B_ * 1024 * D_ / 4) / 256, 256, 0, stream>>>(out, Opart, L0, L1);
}

// Round 3
// 263.381 us; speedup vs baseline: 1.3383x; 1.3383x over previous
//
#include <hip/hip_runtime.h>
#include <hip/hip_bf16.h>
#include <math.h>

// CausalSelfAttention  B=4, S=2048, D=1024, H=16, HD=64
// R9: attn_chunk reverted to R6 (best measured: 95.5us).
//     qkv rewritten as 8-phase counted-vmcnt GEMM (T3+T4+T5):
//       - tile 128(M)x256(N), BK=64, 8 waves (2x4), 512 threads
//       - grid 256 blocks x 3 (QKV) = 768 = 3 x 256 CUs, no tail
//       - ring-3 LDS (144KB): compute t, t+1 resident, t+2 staging
//       - boundary s_waitcnt vmcnt(6) (counted, never hot-drain) + raw s_barrier
//       - 4 phases/K-tile: {ds_read subtile | stage -> bar -> lgkm0 -> 8 MFMA -> bar}
//       - XCD-chunked block swizzle (A-strip sharers on one XCD L2)
//     convert/combine unchanged.

#define B_ 4
#define S_ 2048
#define D_ 1024
#define H_ 16
#define HD_ 64
#define M_ (B_ * S_)   // 8192

typedef unsigned short u16;
typedef unsigned int u32;
typedef __attribute__((ext_vector_type(4))) float f32x4;
typedef __attribute__((ext_vector_type(8))) short bf16x8;   // 8 bf16 in 4 VGPRs

__device__ __forceinline__ u16 f2bfu_rn(float x) {
    u32 u = __builtin_bit_cast(u32, x);
    return (u16)((u + 0x8000u) >> 16);
}

__device__ __forceinline__ void gl2lds16(const void* g, void* l) {
    __builtin_amdgcn_global_load_lds(
        (const __attribute__((address_space(1))) u32*)g,
        (__attribute__((address_space(3))) u32*)l, 16, 0, 0);
}

// ---------------------------------------------------------------------------
// fp32 -> bf16 conversion, 8 elems/thread
// ---------------------------------------------------------------------------
#define XN  8388608u    // 8192*1024
#define WN  1048576u    // 1024*1024
__global__ __launch_bounds__(256) void convert_bf16(
    const float* __restrict__ X,  const float* __restrict__ Wq,
    const float* __restrict__ Wk, const float* __restrict__ Wv,
    u16* __restrict__ Xb, u16* __restrict__ Wqb,
    u16* __restrict__ Wkb, u16* __restrict__ Wvb)
{
    size_t idx = ((size_t)blockIdx.x * 256 + threadIdx.x) * 8;
    const float* src; u16* dst; size_t off;
    if (idx < XN)                { src = X;  dst = Xb;  off = idx; }
    else if (idx < XN + WN)      { src = Wq; dst = Wqb; off = idx - XN; }
    else if (idx < XN + 2 * WN)  { src = Wk; dst = Wkb; off = idx - XN - WN; }
    else                         { src = Wv; dst = Wvb; off = idx - XN - 2 * WN; }
    float4 a = *(const float4*)(src + off);
    float4 b = *(const float4*)(src + off + 4);
    uint4 o;
    o.x = (u32)f2bfu_rn(a.x) | ((u32)f2bfu_rn(a.y) << 16);
    o.y = (u32)f2bfu_rn(a.z) | ((u32)f2bfu_rn(a.w) << 16);
    o.z = (u32)f2bfu_rn(b.x) | ((u32)f2bfu_rn(b.y) << 16);
    o.w = (u32)f2bfu_rn(b.z) | ((u32)f2bfu_rn(b.w) << 16);
    *(uint4*)(dst + off) = o;
}

// ---------------------------------------------------------------------------
// QKV projection GEMM, 8-phase counted-vmcnt schedule.
// C[m][n] = sum_k A[m][k] * B[n][k]  (both operands row-major with K inner)
// z=0: A=X, B=Wq -> Q = (X Wq^T + bq)*QSCALE -> [bh][s][hd]
// z=1: A=X, B=Wk -> K -> [bh][s][hd]
// z=2: A=Wv, B=X -> V^T -> [bh][hd][s]
// Block: 128(M) x 256(N), BK=64, 8 waves as 2(M) x 4(N), per-wave 64x64.
// LDS ring-3: As[3][128][64], Bs[3][256][64] = 144 KB.
// Per wave per K-tile: 6 gl2lds issues (A0,A1,B0,B1,B2,B3) -> vmcnt(6)
// at the tile boundary retires exactly the previous tile's issues.
// ---------------------------------------------------------------------------
#define QSCALE 0.18033688011112042f   // 0.125 * log2(e)

__global__ __launch_bounds__(512) void qkv_mfma8(
    const u16* __restrict__ Xb,
    const u16* __restrict__ Wqb, const u16* __restrict__ Wkb,
    const u16* __restrict__ Wvb,
    const float* __restrict__ bq, const float* __restrict__ bk,
    const float* __restrict__ bv,
    u16* __restrict__ Qb, u16* __restrict__ Kb, u16* __restrict__ Vtb)
{
    const int which = blockIdx.y;
    // XCD-chunked swizzle: phys blockIdx.x round-robins XCDs; give each XCD
    // a contiguous chunk of 32 logical tiles (A-strip sharers co-located).
    const int bxl = ((blockIdx.x & 7) << 5) | (blockIdx.x >> 3);

    const u16* Asrc; const u16* Bsrc; const float* bias; u16* Out;
    int m0, n0;
    if (which == 0)      { Asrc = Xb;  Bsrc = Wqb; bias = bq; Out = Qb;
                           m0 = (bxl >> 2) * 128; n0 = (bxl & 3) * 256; }
    else if (which == 1) { Asrc = Xb;  Bsrc = Wkb; bias = bk; Out = Kb;
                           m0 = (bxl >> 2) * 128; n0 = (bxl & 3) * 256; }
    else                 { Asrc = Wvb; Bsrc = Xb;  bias = bv; Out = Vtb;
                           m0 = (bxl >> 5) * 128; n0 = (bxl & 31) * 256; }

    __shared__ u16 As[3][128][64];   // 48 KB
    __shared__ u16 Bs[3][256][64];   // 96 KB

    const int t = threadIdx.x;
    const int wave = t >> 6, lane = t & 63;
    const int qd = lane >> 4, l15 = lane & 15;
    const int wm = wave >> 2, wn = wave & 3;   // 2 x 4 wave grid

    // stage one 64-row unit of K-tile tt (each wave stages its 8-row slice)
    auto STAGE_A = [&](int tt, int u) {        // u in {0,1}
        const int buf = tt % 3, k0 = tt * 64;
        const int rb = u * 64 + wave * 8;
        const int r  = rb + (lane >> 3);
        const int g  = (lane & 7) ^ (r & 7);
        gl2lds16(Asrc + (size_t)(m0 + r) * D_ + k0 + g * 8, &As[buf][rb][0]);
    };
    auto STAGE_B = [&](int tt, int q) {        // q in {0..3}
        const int buf = tt % 3, k0 = tt * 64;
        const int rb = q * 64 + wave * 8;
        const int r  = rb + (lane >> 3);
        const int g  = (lane & 7) ^ (r & 7);
        gl2lds16(Bsrc + (size_t)(n0 + r) * D_ + k0 + g * 8, &Bs[buf][rb][0]);
    };

    const f32x4 zero = {0.f, 0.f, 0.f, 0.f};
    f32x4 acc[4][4];
#pragma unroll
    for (int i = 0; i < 4; ++i)
#pragma unroll
        for (int j = 0; j < 4; ++j) acc[i][j] = zero;

    // ---- prologue: stage tiles 0 and 1; drain tile 0 only ----
#pragma unroll
    for (int u = 0; u < 2; ++u) STAGE_A(0, u);
#pragma unroll
    for (int q = 0; q < 4; ++q) STAGE_B(0, q);
#pragma unroll
    for (int u = 0; u < 2; ++u) STAGE_A(1, u);
#pragma unroll
    for (int q = 0; q < 4; ++q) STAGE_B(1, q);
    asm volatile("s_waitcnt vmcnt(6)" ::: "memory");
    __builtin_amdgcn_s_barrier();

    for (int tt = 0; tt < 16; ++tt) {
        const int buf = tt % 3;
        const bool st = tt < 14;      // stage tile tt+2 this iteration?
        const int t2 = tt + 2;

        bf16x8 bfv[4][2];
        bf16x8 af[2];

        // ---- phase 1: all B-frags (8 reads) + A-frag mt=0 (2 reads); stage A ----
#pragma unroll
        for (int nt = 0; nt < 4; ++nt) {
            const int row = wn * 64 + nt * 16 + l15;
#pragma unroll
            for (int ks = 0; ks < 2; ++ks)
                bfv[nt][ks] = *(const bf16x8*)&Bs[buf][row][((ks * 4 + qd) ^ (row & 7)) * 8];
        }
        {
            const int row = wm * 64 + l15;
#pragma unroll
            for (int ks = 0; ks < 2; ++ks)
                af[ks] = *(const bf16x8*)&As[buf][row][((ks * 4 + qd) ^ (row & 7)) * 8];
        }
        if (st) { STAGE_A(t2, 0); STAGE_A(t2, 1); }
        __builtin_amdgcn_s_barrier();
        asm volatile("s_waitcnt lgkmcnt(0)" ::: "memory");
        __builtin_amdgcn_sched_barrier(0);
        __builtin_amdgcn_s_setprio(1);
#pragma unroll
        for (int ks = 0; ks < 2; ++ks)
#pragma unroll
            for (int nt = 0; nt < 4; ++nt)
                acc[0][nt] = __builtin_amdgcn_mfma_f32_16x16x32_bf16(
                    af[ks], bfv[nt][ks], acc[0][nt], 0, 0, 0);
        __builtin_amdgcn_s_setprio(0);
        __builtin_amdgcn_s_barrier();

        // ---- phases 2..4: mt = 1..3; stage B0,B1 / B2 / B3 ----
#pragma unroll
        for (int mt = 1; mt < 4; ++mt) {
            const int row = wm * 64 + mt * 16 + l15;
#pragma unroll
            for (int ks = 0; ks < 2; ++ks)
                af[ks] = *(const bf16x8*)&As[buf][row][((ks * 4 + qd) ^ (row & 7)) * 8];
            if (st) {
                if (mt == 1)      { STAGE_B(t2, 0); STAGE_B(t2, 1); }
                else if (mt == 2) { STAGE_B(t2, 2); }
                else              { STAGE_B(t2, 3); }
            }
            __builtin_amdgcn_s_barrier();
            asm volatile("s_waitcnt lgkmcnt(0)" ::: "memory");
            __builtin_amdgcn_sched_barrier(0);
            __builtin_amdgcn_s_setprio(1);
#pragma unroll
            for (int ks = 0; ks < 2; ++ks)
#pragma unroll
                for (int nt = 0; nt < 4; ++nt)
                    acc[mt][nt] = __builtin_amdgcn_mfma_f32_16x16x32_bf16(
                        af[ks], bfv[nt][ks], acc[mt][nt], 0, 0, 0);
            __builtin_amdgcn_s_setprio(0);
            if (mt == 3) {
                // tile boundary: retire previous tile's 6 issues (counted),
                // keep this iteration's 6 in flight.
                if (st) asm volatile("s_waitcnt vmcnt(6)" ::: "memory");
                else    asm volatile("s_waitcnt vmcnt(0)" ::: "memory");
            }
            __builtin_amdgcn_s_barrier();
        }
    }

    // ---- epilogue: C/D layout row = qd*4 + reg, col = l15 ----
    if (which < 2) {
#pragma unroll
        for (int nt = 0; nt < 4; ++nt) {
            int n = n0 + wn * 64 + nt * 16 + l15;      // feature
            float bv_ = bias[n];
            int h = n >> 6, hd = n & 63;
#pragma unroll
            for (int mt = 0; mt < 4; ++mt)
#pragma unroll
                for (int r = 0; r < 4; ++r) {
                    int m = m0 + wm * 64 + mt * 16 + qd * 4 + r;  // token
                    int bb = m >> 11, s = m & 2047;
                    float v = acc[mt][nt][r] + bv_;
                    if (which == 0) v *= QSCALE;
                    Out[(((size_t)(bb * H_ + h)) * S_ + s) * HD_ + hd] = f2bfu_rn(v);
                }
        }
    } else {
#pragma unroll
        for (int mt = 0; mt < 4; ++mt)
#pragma unroll
            for (int r = 0; r < 4; ++r) {
                int f = m0 + wm * 64 + mt * 16 + qd * 4 + r;      // feature
                float bv_ = bias[f];
                int h = f >> 6, hd = f & 63;
#pragma unroll
                for (int nt = 0; nt < 4; ++nt) {
                    int tok = n0 + wn * 64 + nt * 16 + l15;       // token
                    int bb = tok >> 11, s = tok & 2047;
                    float v = acc[mt][nt][r] + bv_;
                    Out[(((size_t)(bb * H_ + h)) * HD_ + hd) * S_ + s] = f2bfu_rn(v);
                }
            }
    }
}

// ---------------------------------------------------------------------------
// Split-K flash attention, deterministic (plain stores only).  [R6, best]
// blockIdx.x in [0,48): x<32 -> chunk0 of qt=31-x (tiles 0..min(qt,15));
//                       x>=32 -> chunk1 of qt=63-x (tiles 16..qt; qt 16..31).
// blockIdx.y = bh.  Heavy blocks at low x (dispatch-order heuristic).
// chunk0, qt<=15 : full row -> normalized result straight to Oout.
// chunk0, qt>=16 : unnormalized O -> Oout, l -> L0.
// chunk1         : unnormalized O -> Opart[bh][s-1024][hd], l -> L1.
// ---------------------------------------------------------------------------
__global__ __launch_bounds__(256) void attn_chunk(
    const u16* __restrict__ Qb, const u16* __restrict__ Kb,
    const u16* __restrict__ Vtb, const int* __restrict__ amask,
    float* __restrict__ Oout, float* __restrict__ Opart,
    float* __restrict__ L0, float* __restrict__ L1)
{
    const int x = blockIdx.x;
    const int bh = blockIdx.y;
    const int b = bh >> 4, h = bh & 15;
    int qt, jt0, jt1; bool second;
    if (x < 32) { qt = 31 - x; jt0 = 0;  jt1 = min(qt, 15); second = false; }
    else        { qt = 63 - x; jt0 = 16; jt1 = qt;          second = true;  }
    const int q0 = qt * 64;

    const int t = threadIdx.x;
    const int wave = t >> 6, lane = t & 63;
    const int qd = lane >> 4, l15 = lane & 15;

    __shared__ u16 Ks[64][64];     // [key][hd]  XOR-swizzled
    __shared__ u16 Vts[64][64];    // [hd][key]  XOR-swizzled
    __shared__ u16 Ps[64][72];     // [q][key]   padded (+8)
    __shared__ float mb[64];       // key mask bias

    const size_t base = (size_t)bh * S_ * HD_;
    const u16* Qg = Qb + base;
    const u16* Kg = Kb + base;
    const u16* Vg = Vtb + base;    // rows = hd, cols = s
    const int* am = amask + b * S_;

    // Q A-frags straight from global (row = q, k = ks*32 + qd*8)
    bf16x8 qf[2];
    {
        const u16* qrow = Qg + (size_t)(q0 + wave * 16 + l15) * HD_;
        qf[0] = *(const bf16x8*)(qrow + qd * 8);
        qf[1] = *(const bf16x8*)(qrow + 32 + qd * 8);
    }
    bf16x8 onesf;
    {
        short v = (l15 == 0) ? (short)0x3F80 : (short)0;
        onesf = (bf16x8){v, v, v, v, v, v, v, v};
    }

    const f32x4 zero = {0.f, 0.f, 0.f, 0.f};
    f32x4 o[5];                    // 4 hd tiles + l tile
#pragma unroll
    for (int i = 0; i < 5; ++i) o[i] = zero;

    for (int jt = jt0; jt <= jt1; ++jt) {
        const int j0 = jt * 64;
        __syncthreads();           // all waves done reading Ks/Vts
#pragma unroll
        for (int i = 0; i < 2; ++i) {
            int r0  = (wave * 2 + i) * 8;
            int row = r0 + (lane >> 3);
            int g   = (lane & 7) ^ (row & 7);
            gl2lds16(Kg + (size_t)(j0 + row) * HD_ + g * 8, &Ks[r0][0]);
            gl2lds16(Vg + (size_t)row * S_ + j0 + g * 8, &Vts[r0][0]);
        }
        if (t < 64) mb[t] = (am[j0 + t] == 0) ? -1e30f : 0.0f;
        __syncthreads();           // staging visible

        // ---- S = Q K^T ----
        f32x4 sacc[4];
#pragma unroll
        for (int nt = 0; nt < 4; ++nt) sacc[nt] = zero;
#pragma unroll
        for (int ks = 0; ks < 2; ++ks) {
#pragma unroll
            for (int nt = 0; nt < 4; ++nt) {
                int brow = nt * 16 + l15;
                int bp = (ks * 4 + qd) ^ (brow & 7);
                bf16x8 bf = *(const bf16x8*)&Ks[brow][bp * 8];
                sacc[nt] = __builtin_amdgcn_mfma_f32_16x16x32_bf16(
                    qf[ks], bf, sacc[nt], 0, 0, 0);
            }
        }

        // ---- bias + causal + exp2 -> Ps (wave-private rows) ----
        float bias[4];
#pragma unroll
        for (int nt = 0; nt < 4; ++nt) bias[nt] = mb[nt * 16 + l15];
        const bool diag = (jt == qt);
#pragma unroll
        for (int r = 0; r < 4; ++r) {
            int prow = wave * 16 + qd * 4 + r;
#pragma unroll
            for (int nt = 0; nt < 4; ++nt) {
                int col = nt * 16 + l15;
                float s = sacc[nt][r] + bias[nt];
                if (diag && col > prow) s = -1e30f;
                float p = __builtin_amdgcn_exp2f(s);
                Ps[prow][col] = f2bfu_rn(p);
            }
        }

        // ---- O += P V ; l += P ones (same-wave LDS rows, no barrier) ----
#pragma unroll
        for (int ks = 0; ks < 2; ++ks) {
            int arow = wave * 16 + l15;
            bf16x8 pf = *(const bf16x8*)&Ps[arow][ks * 32 + qd * 8];
#pragma unroll
            for (int nt = 0; nt < 4; ++nt) {
                int brow = nt * 16 + l15;
                int bp = (ks * 4 + qd) ^ (brow & 7);
                bf16x8 vf = *(const bf16x8*)&Vts[brow][bp * 8];
                o[nt] = __builtin_amdgcn_mfma_f32_16x16x32_bf16(
                    pf, vf, o[nt], 0, 0, 0);
            }
            o[4] = __builtin_amdgcn_mfma_f32_16x16x32_bf16(
                pf, onesf, o[4], 0, 0, 0);
        }
    }

    // ---- epilogue: plain stores (each destination written by ONE block) ----
    if (!second) {
        if (qt <= 15) {
            // full key range: store normalized final value
#pragma unroll
            for (int r = 0; r < 4; ++r) {
                float l = __shfl(o[4][r], lane & 48);
                float inv = 1.0f / l;
                int q = q0 + wave * 16 + qd * 4 + r;
                float* op = Oout + ((size_t)(b * S_ + q)) * D_ + h * HD_;
#pragma unroll
                for (int nt = 0; nt < 4; ++nt)
                    op[nt * 16 + l15] = o[nt][r] * inv;
            }
        } else {
            // partial: unnormalized O -> Oout, l -> L0
#pragma unroll
            for (int r = 0; r < 4; ++r) {
                int q = q0 + wave * 16 + qd * 4 + r;
                float* op = Oout + ((size_t)(b * S_ + q)) * D_ + h * HD_;
#pragma unroll
                for (int nt = 0; nt < 4; ++nt)
                    op[nt * 16 + l15] = o[nt][r];
                if (l15 == 0) L0[(size_t)bh * S_ + q] = o[4][r];
            }
        }
    } else {
#pragma unroll
        for (int r = 0; r < 4; ++r) {
            int q = q0 + wave * 16 + qd * 4 + r;
            int sh = q - 1024;
            float* op = Opart + ((size_t)bh * 1024 + sh) * HD_;
#pragma unroll
            for (int nt = 0; nt < 4; ++nt)
                op[nt * 16 + l15] = o[nt][r];
            if (l15 == 0) L1[(size_t)bh * 1024 + sh] = o[4][r];
        }
    }
}

// ---------------------------------------------------------------------------
// combine: rows s >= 1024 only.  out = (out + Opart) / (L0 + L1).
// i indexes [b][s-1024][d] flat, float4 per thread.
// ---------------------------------------------------------------------------
__global__ __launch_bounds__(256) void combine(
    float* __restrict__ out, const float* __restrict__ Opart,
    const float* __restrict__ L0, const float* __restrict__ L1)
{
    size_t i = ((size_t)blockIdx.x * 256 + threadIdx.x) * 4;
    int d  = (int)(i & (D_ - 1));
    int bs = (int)(i >> 10);          // b*1024 + (s-1024)
    int b  = bs >> 10, sh = bs & 1023;
    int s  = sh + 1024;
    int h  = d >> 6;
    int bh = b * H_ + h;
    float l = L0[(size_t)bh * S_ + s] + L1[(size_t)bh * 1024 + sh];
    float inv = 1.0f / l;
    float* op = out + ((size_t)(b * S_ + s)) * D_ + d;
    const float* pp = Opart + ((size_t)bh * 1024 + sh) * HD_ + (d & 63);
    float4 v = *(float4*)op;
    float4 p = *(const float4*)pp;
    v.x = (v.x + p.x) * inv; v.y = (v.y + p.y) * inv;
    v.z = (v.z + p.z) * inv; v.w = (v.w + p.w) * inv;
    *(float4*)op = v;
}

// ---------------------------------------------------------------------------
extern "C" void kernel_launch(void* const* d_in, const int* in_sizes, int n_in,
                              void* d_out, int out_size, void* d_ws, size_t ws_size,
                              hipStream_t stream) {
    (void)in_sizes; (void)n_in; (void)out_size; (void)ws_size;
    const float* X    = (const float*)d_in[0];
    const int*   mask = (const int*)d_in[1];
    const float* Wq   = (const float*)d_in[2];
    const float* bq   = (const float*)d_in[3];
    const float* Wk   = (const float*)d_in[4];
    const float* bk   = (const float*)d_in[5];
    const float* Wv   = (const float*)d_in[6];
    const float* bv   = (const float*)d_in[7];
    float* out = (float*)d_out;

    u16* Xb  = (u16*)d_ws;                 // 8192x1024 bf16
    u16* Wqb = Xb  + XN;                   // 1024x1024 bf16
    u16* Wkb = Wqb + WN;
    u16* Wvb = Wkb + WN;
    u16* Qb  = Wvb + WN;                   // [bh][s][hd]  (pre-scaled by QSCALE)
    u16* Kb  = Qb  + XN;
    u16* Vtb = Kb  + XN;                   // [bh][hd][s]
    float* Opart = (float*)(Vtb + XN);     // [bh][1024][64] fp32 (16.8 MB)
    float* L0 = Opart + (size_t)64 * 1024 * 64;   // [bh][2048]
    float* L1 = L0 + (size_t)64 * 2048;           // [bh][1024]

    convert_bf16<<<(XN + 3 * WN) / (256 * 8), 256, 0, stream>>>(
        X, Wq, Wk, Wv, Xb, Wqb, Wkb, Wvb);
    qkv_mfma8<<<dim3(256, 3), 512, 0, stream>>>(
        Xb, Wqb, Wkb, Wvb, bq, bk, bv, Qb, Kb, Vtb);
    attn_chunk<<<dim3(48, B_ * H_), 256, 0, stream>>>(
        Qb, Kb, Vtb, mask, out, Opart, L0, L1);
    combine<<<(B_ * 1024 * D_ / 4) / 256, 256, 0, stream>>>(out, Opart, L0, L1);
}